// Round 4
// baseline (1562.584 us; speedup 1.0000x reference)
//
#include <hip/hip_runtime.h>

#define N_NODES 100000
#define N_EDGES 1600000
#define D 64
#define N_GRAPHS 64
#define NBLK ((N_NODES + 255) / 256)   // 391 scan blocks
#define RPW 8                          // rows per wave tile
#define NTILES (N_NODES / RPW)         // 12500
#define AWS 68                         // swizzled aw row stride (floats)

// ---------------- init: deg=1 (self loop), cnt=0, out=0, tile counters=0 ----
__global__ void k_init(float* __restrict__ deg, int* __restrict__ cnt,
                       float* __restrict__ out, int* __restrict__ tc) {
    int i = blockIdx.x * blockDim.x + threadIdx.x;
    if (i < N_NODES) { deg[i] = 1.0f; cnt[i] = 0; }
    if (i < N_GRAPHS * D) out[i] = 0.0f;
    if (i < 2) tc[i] = 0;
}

// ---------------- degree + in-edge count ----------------
__global__ void k_count_deg(const int* __restrict__ dst, const float* __restrict__ ew,
                            float* __restrict__ deg, int* __restrict__ cnt) {
    int e = blockIdx.x * blockDim.x + threadIdx.x;
    if (e < N_EDGES) {
        int d = dst[e];
        atomicAdd(&deg[d], ew[e]);
        atomicAdd(&cnt[d], 1);
    }
}

__global__ void k_dinv(float* __restrict__ deg) {
    int i = blockIdx.x * blockDim.x + threadIdx.x;
    if (i < N_NODES) {
        float d = deg[i];
        deg[i] = d > 0.f ? rsqrtf(d) : 0.f;
    }
}

// ---------------- exclusive scan of cnt -> rowptr ----------------
__global__ void k_scan1(const int* __restrict__ cnt, int* __restrict__ partial,
                        int* __restrict__ bsums) {
    int t = threadIdx.x, b = blockIdx.x, i = b * 256 + t;
    int v = (i < N_NODES) ? cnt[i] : 0;
    int incl = v;
    int lane = t & 63;
#pragma unroll
    for (int off = 1; off < 64; off <<= 1) {
        int u = __shfl_up(incl, off);
        if (lane >= off) incl += u;
    }
    __shared__ int wsum[4];
    int w = t >> 6;
    if (lane == 63) wsum[w] = incl;
    __syncthreads();
    int add = 0;
    for (int k = 0; k < w; ++k) add += wsum[k];
    incl += add;
    if (i < N_NODES) partial[i] = incl;
    if (t == 255) bsums[b] = incl;
}

__global__ void k_scan2(int* __restrict__ bsums) {
    __shared__ int s[512];
    int t = threadIdx.x;
    s[t] = (t < NBLK) ? bsums[t] : 0;
    __syncthreads();
    for (int off = 1; off < 512; off <<= 1) {
        int u = (t >= off) ? s[t - off] : 0;
        __syncthreads();
        s[t] += u;
        __syncthreads();
    }
    if (t < NBLK) bsums[t] = (t == 0) ? 0 : s[t - 1];  // exclusive
}

__global__ void k_scan3(const int* __restrict__ partial, const int* __restrict__ cnt,
                        const int* __restrict__ bsums, int* __restrict__ rowptr,
                        int* __restrict__ cursor) {
    int i = blockIdx.x * 256 + threadIdx.x;
    if (i < N_NODES) {
        int excl = partial[i] - cnt[i] + bsums[blockIdx.x];
        rowptr[i] = excl;
        cursor[i] = excl;
    }
}

// ---------------- scatter edges into CSR (src, norm) grouped by dst ----------
__global__ void k_scatter(const int* __restrict__ src, const int* __restrict__ dst,
                          const float* __restrict__ ew, const float* __restrict__ dinv,
                          int* __restrict__ cursor, float2* __restrict__ csr) {
    int e = blockIdx.x * blockDim.x + threadIdx.x;
    if (e < N_EDGES) {
        int s = src[e];
        int d = dst[e];
        float nrm = dinv[s] * ew[e] * dinv[d];
        int pos = atomicAdd(&cursor[d], 1);
        csr[pos] = make_float2(__int_as_float(s), nrm);
    }
}

// ---------------- fused layer ----------------
// Per wave-tile of 8 rows: gather (A_norm . in) into float4 group-partials,
// reduce, stash in LDS, then 8-row-batched GEMM vs LDS-staged W.
// LAYER==1: write relu(.)  LAYER==2: pool-atomicAdd relu(.) into out[batch].

#define GPASS(P) {                                                         \
    int ei = 4 * (P) + g;                                                  \
    bool act = ei < dg;                                                    \
    float2 sw = csr[st + (act ? ei : 0)];                                  \
    float wgt = act ? sw.y : 0.0f;                                         \
    int sidx = __float_as_int(sw.x);                                       \
    float4 v = in4[sidx * 16 + q];                                         \
    acc.x = fmaf(v.x, wgt, acc.x);                                         \
    acc.y = fmaf(v.y, wgt, acc.y);                                         \
    acc.z = fmaf(v.z, wgt, acc.z);                                         \
    acc.w = fmaf(v.w, wgt, acc.w); }

template <int LAYER>
__global__ __launch_bounds__(256) void k_fused(
        const float* __restrict__ in, const float* __restrict__ W,
        const float* __restrict__ bias, const float* __restrict__ dinv,
        const int* __restrict__ rowptr, const int* __restrict__ cnt,
        const float2* __restrict__ csr, const int* __restrict__ batch,
        float* __restrict__ outp, int* __restrict__ tc) {
    __shared__ float Ws[D * D];          // 16 KB
    __shared__ float aw[4][RPW * AWS];   // 4 waves x 8 rows x 68 floats
    __shared__ float bs[D];

    {   // stage W (float4) + bias
        const float4* Wg = (const float4*)W;
        float4* Wl = (float4*)Ws;
        int t = threadIdx.x;
#pragma unroll
        for (int i = 0; i < 4; ++i) Wl[t + i * 256] = Wg[t + i * 256];
        if (t < D) bs[t] = bias[t];
    }
    __syncthreads();

    const int lane = threadIdx.x & 63;
    const int wid  = threadIdx.x >> 6;
    const int g    = lane >> 4;      // 0..3  edge group / row group
    const int q    = lane & 15;      // 0..15 column block
    const float4* in4 = (const float4*)in;
    const float4* Ws4 = (const float4*)Ws;
    float* awm = aw[wid];

    int tile;
    if (lane == 0) tile = atomicAdd(tc, 1);
    tile = __builtin_amdgcn_readfirstlane(tile);

    while (tile < NTILES) {
        const int base = tile * RPW;

        // ---- gather 8 rows ----
        for (int rr = 0; rr < RPW; ++rr) {
            const int row = base + rr;
            int st = __builtin_amdgcn_readfirstlane(rowptr[row]);
            int dg = __builtin_amdgcn_readfirstlane(cnt[row]);
            float4 acc = make_float4(0.f, 0.f, 0.f, 0.f);
            if (g == 0) {
                float di = dinv[row];
                float4 s4 = in4[row * 16 + q];
                float d2 = di * di;
                acc.x = s4.x * d2; acc.y = s4.y * d2;
                acc.z = s4.z * d2; acc.w = s4.w * d2;
            }
            const int passes = (dg + 3) >> 2;
            int p = 0;
            for (; p + 4 <= passes; p += 4) {
                GPASS(p) GPASS(p + 1) GPASS(p + 2) GPASS(p + 3)
            }
            for (; p < passes; ++p) { GPASS(p) }
            // reduce the 4 group-partials (same q across g)
            acc.x += __shfl_xor(acc.x, 16); acc.y += __shfl_xor(acc.y, 16);
            acc.z += __shfl_xor(acc.z, 16); acc.w += __shfl_xor(acc.w, 16);
            acc.x += __shfl_xor(acc.x, 32); acc.y += __shfl_xor(acc.y, 32);
            acc.z += __shfl_xor(acc.z, 32); acc.w += __shfl_xor(acc.w, 32);
            if (g == 0) *(float4*)&awm[rr * AWS + q * 4] = acc;
        }
        // wave-internal LDS RAW: in-order LDS pipe, same wave -> no barrier.

        // ---- 8-row GEMM: lane (g,q) -> rows {g, g+4}, cols 4q..4q+3 ----
        float4 r0 = make_float4(0.f, 0.f, 0.f, 0.f);
        float4 r1 = make_float4(0.f, 0.f, 0.f, 0.f);
#pragma unroll
        for (int t = 0; t < 16; ++t) {
            float4 a0 = *(const float4*)&awm[(g)     * AWS + t * 4];
            float4 a1 = *(const float4*)&awm[(g + 4) * AWS + t * 4];
            float4 w;
            w = Ws4[(4 * t + 0) * 16 + q];
            r0.x = fmaf(a0.x, w.x, r0.x); r0.y = fmaf(a0.x, w.y, r0.y);
            r0.z = fmaf(a0.x, w.z, r0.z); r0.w = fmaf(a0.x, w.w, r0.w);
            r1.x = fmaf(a1.x, w.x, r1.x); r1.y = fmaf(a1.x, w.y, r1.y);
            r1.z = fmaf(a1.x, w.z, r1.z); r1.w = fmaf(a1.x, w.w, r1.w);
            w = Ws4[(4 * t + 1) * 16 + q];
            r0.x = fmaf(a0.y, w.x, r0.x); r0.y = fmaf(a0.y, w.y, r0.y);
            r0.z = fmaf(a0.y, w.z, r0.z); r0.w = fmaf(a0.y, w.w, r0.w);
            r1.x = fmaf(a1.y, w.x, r1.x); r1.y = fmaf(a1.y, w.y, r1.y);
            r1.z = fmaf(a1.y, w.z, r1.z); r1.w = fmaf(a1.y, w.w, r1.w);
            w = Ws4[(4 * t + 2) * 16 + q];
            r0.x = fmaf(a0.z, w.x, r0.x); r0.y = fmaf(a0.z, w.y, r0.y);
            r0.z = fmaf(a0.z, w.z, r0.z); r0.w = fmaf(a0.z, w.w, r0.w);
            r1.x = fmaf(a1.z, w.x, r1.x); r1.y = fmaf(a1.z, w.y, r1.y);
            r1.z = fmaf(a1.z, w.z, r1.z); r1.w = fmaf(a1.z, w.w, r1.w);
            w = Ws4[(4 * t + 3) * 16 + q];
            r0.x = fmaf(a0.w, w.x, r0.x); r0.y = fmaf(a0.w, w.y, r0.y);
            r0.z = fmaf(a0.w, w.z, r0.z); r0.w = fmaf(a0.w, w.w, r0.w);
            r1.x = fmaf(a1.w, w.x, r1.x); r1.y = fmaf(a1.w, w.y, r1.y);
            r1.z = fmaf(a1.w, w.z, r1.z); r1.w = fmaf(a1.w, w.w, r1.w);
        }
        {   // bias + relu
            float4 b4 = *(const float4*)&bs[q * 4];
            r0.x = fmaxf(r0.x + b4.x, 0.f); r0.y = fmaxf(r0.y + b4.y, 0.f);
            r0.z = fmaxf(r0.z + b4.z, 0.f); r0.w = fmaxf(r0.w + b4.w, 0.f);
            r1.x = fmaxf(r1.x + b4.x, 0.f); r1.y = fmaxf(r1.y + b4.y, 0.f);
            r1.z = fmaxf(r1.z + b4.z, 0.f); r1.w = fmaxf(r1.w + b4.w, 0.f);
        }
        if (LAYER == 1) {
            float4* o4 = (float4*)outp;
            o4[(base + g)     * 16 + q] = r0;
            o4[(base + g + 4) * 16 + q] = r1;
        } else {
            int b0 = batch[base + g];
            int b1 = batch[base + g + 4];
            atomicAdd(&outp[b0 * D + q * 4 + 0], r0.x);
            atomicAdd(&outp[b0 * D + q * 4 + 1], r0.y);
            atomicAdd(&outp[b0 * D + q * 4 + 2], r0.z);
            atomicAdd(&outp[b0 * D + q * 4 + 3], r0.w);
            atomicAdd(&outp[b1 * D + q * 4 + 0], r1.x);
            atomicAdd(&outp[b1 * D + q * 4 + 1], r1.y);
            atomicAdd(&outp[b1 * D + q * 4 + 2], r1.z);
            atomicAdd(&outp[b1 * D + q * 4 + 3], r1.w);
        }

        if (lane == 0) tile = atomicAdd(tc, 1);
        tile = __builtin_amdgcn_readfirstlane(tile);
    }
}

// ---------------- finalize pool: divide by per-graph node count ----------------
__global__ void k_finalize(float* __restrict__ out, const int* __restrict__ batch) {
    int g = blockIdx.x;
    int lane = threadIdx.x;
    int lo = 0, hi = N_NODES;
    while (lo < hi) { int m = (lo + hi) >> 1; if (batch[m] < g) lo = m + 1; else hi = m; }
    int start = lo;
    hi = N_NODES;
    while (lo < hi) { int m = (lo + hi) >> 1; if (batch[m] < g + 1) lo = m + 1; else hi = m; }
    float c = (float)(lo - start);
    out[g * D + lane] /= fmaxf(c, 1.0f);
}

// ---------------- launch ----------------
extern "C" void kernel_launch(void* const* d_in, const int* in_sizes, int n_in,
                              void* d_out, int out_size, void* d_ws, size_t ws_size,
                              hipStream_t stream) {
    const float* x     = (const float*)d_in[0];
    const int*   ei    = (const int*)d_in[1];
    const int*   src   = ei;
    const int*   dst   = ei + N_EDGES;
    const int*   batch = (const int*)d_in[2];
    const float* ew    = (const float*)d_in[3];
    const float* W1    = (const float*)d_in[4];
    const float* b1    = (const float*)d_in[5];
    const float* W2    = (const float*)d_in[6];
    const float* b2    = (const float*)d_in[7];
    float* out = (float*)d_out;

    char* ws = (char*)d_ws;
    float*  bufA   = (float*)(ws);                    // 25.6 MB  h1
    float2* csr    = (float2*)(ws + 25600000);        // 12.8 MB  (src, norm)
    float*  deg    = (float*)(ws + 38400000);         // 400 KB   deg -> dinv
    int*    cnt    = (int*)(ws + 38800000);           // 400 KB
    int*    rowptr = (int*)(ws + 39200000);           // 400 KB
    int*    cursor = (int*)(ws + 39600000);           // 400 KB
    int*    bsums  = (int*)(ws + 40000000);           // 2 KB
    int*    tc     = (int*)(ws + 40004096);           // 2 ints (tile counters)

    // normalization + CSR build
    k_init<<<NBLK, 256, 0, stream>>>(deg, cnt, out, tc);
    k_count_deg<<<(N_EDGES + 255) / 256, 256, 0, stream>>>(dst, ew, deg, cnt);
    k_dinv<<<NBLK, 256, 0, stream>>>(deg);
    k_scan1<<<NBLK, 256, 0, stream>>>(cnt, rowptr, bsums);
    k_scan2<<<1, 512, 0, stream>>>(bsums);
    k_scan3<<<NBLK, 256, 0, stream>>>(rowptr, cnt, bsums, rowptr, cursor);
    k_scatter<<<(N_EDGES + 255) / 256, 256, 0, stream>>>(src, dst, ew, deg, cursor, csr);

    // layer 1: bufA = relu((A x) W1 + b1)
    k_fused<1><<<1024, 256, 0, stream>>>(x, W1, b1, deg, rowptr, cnt, csr, batch, bufA, tc);
    // layer 2 + pool-sum: out[g] += relu((A bufA) W2 + b2)
    k_fused<2><<<1024, 256, 0, stream>>>(bufA, W2, b2, deg, rowptr, cnt, csr, batch, out, tc + 1);
    // mean
    k_finalize<<<N_GRAPHS, D, 0, stream>>>(out, batch);
}

// Round 5
// 1306.243 us; speedup vs baseline: 1.1962x; 1.1962x over previous
//
#include <hip/hip_runtime.h>

#define N_NODES 100000
#define N_EDGES 1600000
#define D 64
#define N_GRAPHS 64
#define NBLK ((N_NODES + 255) / 256)   // 391 scan blocks
#define AWS 68                         // swizzled aw row stride (floats)

// ---------------- init: deg=1 (self loop), cnt=0, out=0 ----------------
__global__ void k_init(float* __restrict__ deg, int* __restrict__ cnt,
                       float* __restrict__ out) {
    int i = blockIdx.x * blockDim.x + threadIdx.x;
    if (i < N_NODES) { deg[i] = 1.0f; cnt[i] = 0; }
    if (i < N_GRAPHS * D) out[i] = 0.0f;
}

// ---------------- degree + in-edge count ----------------
__global__ void k_count_deg(const int* __restrict__ dst, const float* __restrict__ ew,
                            float* __restrict__ deg, int* __restrict__ cnt) {
    int e = blockIdx.x * blockDim.x + threadIdx.x;
    if (e < N_EDGES) {
        int d = dst[e];
        atomicAdd(&deg[d], ew[e]);
        atomicAdd(&cnt[d], 1);
    }
}

__global__ void k_dinv(float* __restrict__ deg) {
    int i = blockIdx.x * blockDim.x + threadIdx.x;
    if (i < N_NODES) {
        float d = deg[i];
        deg[i] = d > 0.f ? rsqrtf(d) : 0.f;
    }
}

// ---------------- exclusive scan of cnt -> rowptr ----------------
__global__ void k_scan1(const int* __restrict__ cnt, int* __restrict__ partial,
                        int* __restrict__ bsums) {
    int t = threadIdx.x, b = blockIdx.x, i = b * 256 + t;
    int v = (i < N_NODES) ? cnt[i] : 0;
    int incl = v;
    int lane = t & 63;
#pragma unroll
    for (int off = 1; off < 64; off <<= 1) {
        int u = __shfl_up(incl, off);
        if (lane >= off) incl += u;
    }
    __shared__ int wsum[4];
    int w = t >> 6;
    if (lane == 63) wsum[w] = incl;
    __syncthreads();
    int add = 0;
    for (int k = 0; k < w; ++k) add += wsum[k];
    incl += add;
    if (i < N_NODES) partial[i] = incl;
    if (t == 255) bsums[b] = incl;
}

__global__ void k_scan2(int* __restrict__ bsums) {
    __shared__ int s[512];
    int t = threadIdx.x;
    s[t] = (t < NBLK) ? bsums[t] : 0;
    __syncthreads();
    for (int off = 1; off < 512; off <<= 1) {
        int u = (t >= off) ? s[t - off] : 0;
        __syncthreads();
        s[t] += u;
        __syncthreads();
    }
    if (t < NBLK) bsums[t] = (t == 0) ? 0 : s[t - 1];  // exclusive
}

__global__ void k_scan3(const int* __restrict__ partial, const int* __restrict__ cnt,
                        const int* __restrict__ bsums, int* __restrict__ rowptr,
                        int* __restrict__ cursor) {
    int i = blockIdx.x * 256 + threadIdx.x;
    if (i < N_NODES) {
        int excl = partial[i] - cnt[i] + bsums[blockIdx.x];
        rowptr[i] = excl;
        cursor[i] = excl;
    }
}

// ---------------- scatter edges into CSR (src, norm) grouped by dst ----------
__global__ void k_scatter(const int* __restrict__ src, const int* __restrict__ dst,
                          const float* __restrict__ ew, const float* __restrict__ dinv,
                          int* __restrict__ cursor, float2* __restrict__ csr) {
    int e = blockIdx.x * blockDim.x + threadIdx.x;
    if (e < N_EDGES) {
        int s = src[e];
        int d = dst[e];
        float nrm = dinv[s] * ew[e] * dinv[d];
        int pos = atomicAdd(&cursor[d], 1);
        csr[pos] = make_float2(__int_as_float(s), nrm);
    }
}

// ---------------- fused layer ----------------
// Per wave: gather 4 rows (round-3 proven structure: coalesced csr chunk,
// shfl broadcast, 8 independent gathers in flight), stash rows in LDS, then
// 4-row-batched GEMM with float4 LDS reads (few LDS-pipe ops).
// LAYER==1: write relu(.)  LAYER==2: pool-atomicAdd relu(.) into out[batch].
template <int LAYER>
__global__ __launch_bounds__(256) void k_layer(
        const float* __restrict__ in, const float* __restrict__ W,
        const float* __restrict__ bias, const float* __restrict__ dinv,
        const int* __restrict__ rowptr, const int* __restrict__ cnt,
        const float2* __restrict__ csr, const int* __restrict__ batch,
        float* __restrict__ outp) {
    __shared__ float Ws[D * D];          // 16 KB
    __shared__ float aw[4][4 * AWS];     // per-wave 4-row staging (4.25 KB)
    __shared__ float bs[D];

    {   // stage W (float4) + bias
        const float4* Wg = (const float4*)W;
        float4* Wl = (float4*)Ws;
        int t = threadIdx.x;
#pragma unroll
        for (int i = 0; i < 4; ++i) Wl[t + i * 256] = Wg[t + i * 256];
        if (t < D) bs[t] = bias[t];
    }
    __syncthreads();

    const int lane = threadIdx.x & 63;
    const int wid  = threadIdx.x >> 6;
    const int g    = lane >> 4;      // 0..3  row within batch (GEMM phase)
    const int q    = lane & 15;      // 0..15 column block (GEMM phase)
    float* awm = aw[wid];

    int gw = (blockIdx.x * blockDim.x + threadIdx.x) >> 6;
    const int tw = (gridDim.x * blockDim.x) >> 6;
    const int NB = N_NODES / 4;      // 25000 batches of 4 rows

    for (int bt = gw; bt < NB; bt += tw) {
        const int base = bt * 4;

        // ---- phase A: gather 4 rows (lane = column) ----
        for (int rr = 0; rr < 4; ++rr) {
            const int row = base + rr;
            float di = dinv[row];
            float acc = in[row * D + lane] * (di * di);   // self-loop
            const int st = rowptr[row];
            const int dg = cnt[row];

            for (int eb = 0; eb < dg; eb += 64) {
                int rem = dg - eb;
                int n = rem < 64 ? rem : 64;
                float2 my = make_float2(0.f, 0.f);
                if (lane < n) my = csr[st + eb + lane];

                int j = 0;
                for (; j + 8 <= n; j += 8) {
                    int   s0 = __float_as_int(__shfl(my.x, j + 0));
                    int   s1 = __float_as_int(__shfl(my.x, j + 1));
                    int   s2 = __float_as_int(__shfl(my.x, j + 2));
                    int   s3 = __float_as_int(__shfl(my.x, j + 3));
                    int   s4 = __float_as_int(__shfl(my.x, j + 4));
                    int   s5 = __float_as_int(__shfl(my.x, j + 5));
                    int   s6 = __float_as_int(__shfl(my.x, j + 6));
                    int   s7 = __float_as_int(__shfl(my.x, j + 7));
                    float w0 = __shfl(my.y, j + 0);
                    float w1 = __shfl(my.y, j + 1);
                    float w2 = __shfl(my.y, j + 2);
                    float w3 = __shfl(my.y, j + 3);
                    float w4 = __shfl(my.y, j + 4);
                    float w5 = __shfl(my.y, j + 5);
                    float w6 = __shfl(my.y, j + 6);
                    float w7 = __shfl(my.y, j + 7);
                    float v0 = in[s0 * D + lane];
                    float v1 = in[s1 * D + lane];
                    float v2 = in[s2 * D + lane];
                    float v3 = in[s3 * D + lane];
                    float v4 = in[s4 * D + lane];
                    float v5 = in[s5 * D + lane];
                    float v6 = in[s6 * D + lane];
                    float v7 = in[s7 * D + lane];
                    acc = fmaf(v0, w0, acc);
                    acc = fmaf(v1, w1, acc);
                    acc = fmaf(v2, w2, acc);
                    acc = fmaf(v3, w3, acc);
                    acc = fmaf(v4, w4, acc);
                    acc = fmaf(v5, w5, acc);
                    acc = fmaf(v6, w6, acc);
                    acc = fmaf(v7, w7, acc);
                }
                for (; j < n; ++j) {
                    int   s0 = __float_as_int(__shfl(my.x, j));
                    float w0 = __shfl(my.y, j);
                    acc = fmaf(in[s0 * D + lane], w0, acc);
                }
            }
            awm[rr * AWS + lane] = acc;   // same-wave LDS, in-order: no barrier
        }

        // ---- phase B: 4-row batched GEMM from LDS ----
        // lane (g,q): row base+g, cols 4q..4q+3
        float4 r = make_float4(0.f, 0.f, 0.f, 0.f);
        const float4* Ws4 = (const float4*)Ws;
#pragma unroll
        for (int t = 0; t < 16; ++t) {
            float4 a  = *(const float4*)&awm[g * AWS + t * 4];
            float4 w0 = Ws4[(4 * t + 0) * 16 + q];
            float4 w1 = Ws4[(4 * t + 1) * 16 + q];
            float4 w2 = Ws4[(4 * t + 2) * 16 + q];
            float4 w3 = Ws4[(4 * t + 3) * 16 + q];
            r.x = fmaf(a.x, w0.x, r.x); r.y = fmaf(a.x, w0.y, r.y);
            r.z = fmaf(a.x, w0.z, r.z); r.w = fmaf(a.x, w0.w, r.w);
            r.x = fmaf(a.y, w1.x, r.x); r.y = fmaf(a.y, w1.y, r.y);
            r.z = fmaf(a.y, w1.z, r.z); r.w = fmaf(a.y, w1.w, r.w);
            r.x = fmaf(a.z, w2.x, r.x); r.y = fmaf(a.z, w2.y, r.y);
            r.z = fmaf(a.z, w2.z, r.z); r.w = fmaf(a.z, w2.w, r.w);
            r.x = fmaf(a.w, w3.x, r.x); r.y = fmaf(a.w, w3.y, r.y);
            r.z = fmaf(a.w, w3.z, r.z); r.w = fmaf(a.w, w3.w, r.w);
        }
        {   // bias + relu
            float4 b4 = *(const float4*)&bs[q * 4];
            r.x = fmaxf(r.x + b4.x, 0.f); r.y = fmaxf(r.y + b4.y, 0.f);
            r.z = fmaxf(r.z + b4.z, 0.f); r.w = fmaxf(r.w + b4.w, 0.f);
        }

        if (LAYER == 1) {
            ((float4*)outp)[(base + g) * 16 + q] = r;
        } else {
            int bg = batch[base + g];
            atomicAdd(&outp[bg * D + q * 4 + 0], r.x);
            atomicAdd(&outp[bg * D + q * 4 + 1], r.y);
            atomicAdd(&outp[bg * D + q * 4 + 2], r.z);
            atomicAdd(&outp[bg * D + q * 4 + 3], r.w);
        }
    }
}

// ---------------- finalize pool: divide by per-graph node count ----------------
__global__ void k_finalize(float* __restrict__ out, const int* __restrict__ batch) {
    int g = blockIdx.x;
    int lane = threadIdx.x;
    int lo = 0, hi = N_NODES;
    while (lo < hi) { int m = (lo + hi) >> 1; if (batch[m] < g) lo = m + 1; else hi = m; }
    int start = lo;
    hi = N_NODES;
    while (lo < hi) { int m = (lo + hi) >> 1; if (batch[m] < g + 1) lo = m + 1; else hi = m; }
    float c = (float)(lo - start);
    out[g * D + lane] /= fmaxf(c, 1.0f);
}

// ---------------- launch ----------------
extern "C" void kernel_launch(void* const* d_in, const int* in_sizes, int n_in,
                              void* d_out, int out_size, void* d_ws, size_t ws_size,
                              hipStream_t stream) {
    const float* x     = (const float*)d_in[0];
    const int*   ei    = (const int*)d_in[1];
    const int*   src   = ei;
    const int*   dst   = ei + N_EDGES;
    const int*   batch = (const int*)d_in[2];
    const float* ew    = (const float*)d_in[3];
    const float* W1    = (const float*)d_in[4];
    const float* b1    = (const float*)d_in[5];
    const float* W2    = (const float*)d_in[6];
    const float* b2    = (const float*)d_in[7];
    float* out = (float*)d_out;

    char* ws = (char*)d_ws;
    float*  bufA   = (float*)(ws);                    // 25.6 MB  h1
    float2* csr    = (float2*)(ws + 25600000);        // 12.8 MB  (src, norm)
    float*  deg    = (float*)(ws + 38400000);         // 400 KB   deg -> dinv
    int*    cnt    = (int*)(ws + 38800000);           // 400 KB
    int*    rowptr = (int*)(ws + 39200000);           // 400 KB
    int*    cursor = (int*)(ws + 39600000);           // 400 KB
    int*    bsums  = (int*)(ws + 40000000);           // 2 KB

    // normalization + CSR build
    k_init<<<NBLK, 256, 0, stream>>>(deg, cnt, out);
    k_count_deg<<<(N_EDGES + 255) / 256, 256, 0, stream>>>(dst, ew, deg, cnt);
    k_dinv<<<NBLK, 256, 0, stream>>>(deg);
    k_scan1<<<NBLK, 256, 0, stream>>>(cnt, rowptr, bsums);
    k_scan2<<<1, 512, 0, stream>>>(bsums);
    k_scan3<<<NBLK, 256, 0, stream>>>(rowptr, cnt, bsums, rowptr, cursor);
    k_scatter<<<(N_EDGES + 255) / 256, 256, 0, stream>>>(src, dst, ew, deg, cursor, csr);

    // layer 1: bufA = relu((A x) W1 + b1)
    k_layer<1><<<2048, 256, 0, stream>>>(x, W1, b1, deg, rowptr, cnt, csr, batch, bufA);
    // layer 2 + pool-sum: out[g] += relu((A bufA) W2 + b2)
    k_layer<2><<<2048, 256, 0, stream>>>(bufA, W2, b2, deg, rowptr, cnt, csr, batch, out);
    // mean
    k_finalize<<<N_GRAPHS, D, 0, stream>>>(out, batch);
}

// Round 6
// 522.989 us; speedup vs baseline: 2.9878x; 2.4976x over previous
//
#include <hip/hip_runtime.h>

#define N_NODES 100000
#define N_EDGES 1600000
#define D 64
#define N_GRAPHS 64
#define NBLK ((N_NODES + 255) / 256)   // 391 scan blocks
#define WTS 68                         // WT row stride (floats): conflict-free

// ---------------- init: deg=1 (self loop), cnt=0, out=0 ----------------
__global__ void k_init(float* __restrict__ deg, int* __restrict__ cnt,
                       float* __restrict__ out) {
    int i = blockIdx.x * blockDim.x + threadIdx.x;
    if (i < N_NODES) { deg[i] = 1.0f; cnt[i] = 0; }
    if (i < N_GRAPHS * D) out[i] = 0.0f;
}

// ---------------- degree + in-edge count ----------------
__global__ void k_count_deg(const int* __restrict__ dst, const float* __restrict__ ew,
                            float* __restrict__ deg, int* __restrict__ cnt) {
    int e = blockIdx.x * blockDim.x + threadIdx.x;
    if (e < N_EDGES) {
        int d = dst[e];
        atomicAdd(&deg[d], ew[e]);
        atomicAdd(&cnt[d], 1);
    }
}

__global__ void k_dinv(float* __restrict__ deg) {
    int i = blockIdx.x * blockDim.x + threadIdx.x;
    if (i < N_NODES) {
        float d = deg[i];
        deg[i] = d > 0.f ? rsqrtf(d) : 0.f;
    }
}

// ---------------- exclusive scan of cnt -> rowptr ----------------
__global__ void k_scan1(const int* __restrict__ cnt, int* __restrict__ partial,
                        int* __restrict__ bsums) {
    int t = threadIdx.x, b = blockIdx.x, i = b * 256 + t;
    int v = (i < N_NODES) ? cnt[i] : 0;
    int incl = v;
    int lane = t & 63;
#pragma unroll
    for (int off = 1; off < 64; off <<= 1) {
        int u = __shfl_up(incl, off);
        if (lane >= off) incl += u;
    }
    __shared__ int wsum[4];
    int w = t >> 6;
    if (lane == 63) wsum[w] = incl;
    __syncthreads();
    int add = 0;
    for (int k = 0; k < w; ++k) add += wsum[k];
    incl += add;
    if (i < N_NODES) partial[i] = incl;
    if (t == 255) bsums[b] = incl;
}

__global__ void k_scan2(int* __restrict__ bsums) {
    __shared__ int s[512];
    int t = threadIdx.x;
    s[t] = (t < NBLK) ? bsums[t] : 0;
    __syncthreads();
    for (int off = 1; off < 512; off <<= 1) {
        int u = (t >= off) ? s[t - off] : 0;
        __syncthreads();
        s[t] += u;
        __syncthreads();
    }
    if (t < NBLK) bsums[t] = (t == 0) ? 0 : s[t - 1];  // exclusive
}

__global__ void k_scan3(const int* __restrict__ partial, const int* __restrict__ cnt,
                        const int* __restrict__ bsums, int* __restrict__ rowptr,
                        int* __restrict__ cursor) {
    int i = blockIdx.x * 256 + threadIdx.x;
    if (i < N_NODES) {
        int excl = partial[i] - cnt[i] + bsums[blockIdx.x];
        rowptr[i] = excl;
        cursor[i] = excl;
    }
}

// ---------------- scatter edges into CSR (src, norm) grouped by dst ----------
__global__ void k_scatter(const int* __restrict__ src, const int* __restrict__ dst,
                          const float* __restrict__ ew, const float* __restrict__ dinv,
                          int* __restrict__ cursor, float2* __restrict__ csr) {
    int e = blockIdx.x * blockDim.x + threadIdx.x;
    if (e < N_EDGES) {
        int s = src[e];
        int d = dst[e];
        float nrm = dinv[s] * ew[e] * dinv[d];
        int pos = atomicAdd(&cursor[d], 1);
        csr[pos] = make_float2(__int_as_float(s), nrm);
    }
}

// ---------------- fused layer ----------------
// One row per wave-iteration (round-3 shape, VGPR-lean). Gather uses
// wave-uniform scalar csr reads + readfirstlane'd src indices: no LDS ops.
// GEMM reads the lane's W-column from transposed-W LDS as float4 (stride 68 =
// conflict-free) and acc via 1 ds_write + broadcast float4 reads.
// LAYER==1: write relu(.)  LAYER==2: pool-atomicAdd relu(.) into out[batch].
template <int LAYER>
__global__ __launch_bounds__(256) void k_layer(
        const float* __restrict__ in, const float* __restrict__ W,
        const float* __restrict__ bias, const float* __restrict__ dinv,
        const int* __restrict__ rowptr, const int* __restrict__ cnt,
        const float2* __restrict__ csr, const int* __restrict__ batch,
        float* __restrict__ outp) {
    __shared__ float WTs[D * WTS];       // 17408 B transposed W
    __shared__ float aw[4][WTS];         // per-wave row staging
    __shared__ float bs[D];

    {   // stage W transposed: WTs[c*WTS + k] = W[k*D + c]
        int t = threadIdx.x;
#pragma unroll
        for (int i = 0; i < 16; ++i) {
            int idx = t + i * 256;
            int k = idx >> 6, c = idx & 63;
            WTs[c * WTS + k] = W[idx];
        }
        if (t < D) bs[t] = bias[t];
    }
    __syncthreads();

    const int lane = threadIdx.x & 63;
    const int wid  = threadIdx.x >> 6;
    float* awm = aw[wid];
    const float bl = bs[lane];   // one LDS read; stays in a register

    int gw = (blockIdx.x * blockDim.x + threadIdx.x) >> 6;
    const int tw = (gridDim.x * blockDim.x) >> 6;

    for (int row = gw; row < N_NODES; row += tw) {
        const int st = __builtin_amdgcn_readfirstlane(rowptr[row]);
        const int dg = __builtin_amdgcn_readfirstlane(cnt[row]);
        float di = dinv[row];
        float acc = in[row * D + lane] * (di * di);   // self-loop

        int j = 0;
        for (; j + 8 <= dg; j += 8) {
            // wave-uniform csr reads (scalarizable) — no shfl/LDS
            float2 e0 = csr[st + j + 0];
            float2 e1 = csr[st + j + 1];
            float2 e2 = csr[st + j + 2];
            float2 e3 = csr[st + j + 3];
            float2 e4 = csr[st + j + 4];
            float2 e5 = csr[st + j + 5];
            float2 e6 = csr[st + j + 6];
            float2 e7 = csr[st + j + 7];
            int s0 = __builtin_amdgcn_readfirstlane(__float_as_int(e0.x));
            int s1 = __builtin_amdgcn_readfirstlane(__float_as_int(e1.x));
            int s2 = __builtin_amdgcn_readfirstlane(__float_as_int(e2.x));
            int s3 = __builtin_amdgcn_readfirstlane(__float_as_int(e3.x));
            int s4 = __builtin_amdgcn_readfirstlane(__float_as_int(e4.x));
            int s5 = __builtin_amdgcn_readfirstlane(__float_as_int(e5.x));
            int s6 = __builtin_amdgcn_readfirstlane(__float_as_int(e6.x));
            int s7 = __builtin_amdgcn_readfirstlane(__float_as_int(e7.x));
            float v0 = in[s0 * D + lane];
            float v1 = in[s1 * D + lane];
            float v2 = in[s2 * D + lane];
            float v3 = in[s3 * D + lane];
            float v4 = in[s4 * D + lane];
            float v5 = in[s5 * D + lane];
            float v6 = in[s6 * D + lane];
            float v7 = in[s7 * D + lane];
            acc = fmaf(v0, e0.y, acc);
            acc = fmaf(v1, e1.y, acc);
            acc = fmaf(v2, e2.y, acc);
            acc = fmaf(v3, e3.y, acc);
            acc = fmaf(v4, e4.y, acc);
            acc = fmaf(v5, e5.y, acc);
            acc = fmaf(v6, e6.y, acc);
            acc = fmaf(v7, e7.y, acc);
        }
        for (; j < dg; ++j) {
            float2 e = csr[st + j];
            int s0 = __builtin_amdgcn_readfirstlane(__float_as_int(e.x));
            acc = fmaf(in[s0 * D + lane], e.y, acc);
        }

        // ---- GEMM: r[lane] = sum_k acc[k] * W[k][lane] ----
        awm[lane] = acc;   // same-wave LDS RAW; compiler inserts lgkmcnt wait
        float r0 = 0.f, r1 = 0.f, r2 = 0.f, r3 = 0.f;
#pragma unroll
        for (int t = 0; t < 16; ++t) {
            float4 a = *(const float4*)&awm[t * 4];                // broadcast
            float4 w = *(const float4*)&WTs[lane * WTS + t * 4];   // conflict-free
            r0 = fmaf(a.x, w.x, r0);
            r1 = fmaf(a.y, w.y, r1);
            r2 = fmaf(a.z, w.z, r2);
            r3 = fmaf(a.w, w.w, r3);
        }
        float r = fmaxf((r0 + r1) + (r2 + r3) + bl, 0.f);

        if (LAYER == 1) {
            outp[row * D + lane] = r;
        } else {
            atomicAdd(&outp[batch[row] * D + lane], r);
        }
    }
}

// ---------------- finalize pool: divide by per-graph node count ----------------
__global__ void k_finalize(float* __restrict__ out, const int* __restrict__ batch) {
    int g = blockIdx.x;
    int lane = threadIdx.x;
    int lo = 0, hi = N_NODES;
    while (lo < hi) { int m = (lo + hi) >> 1; if (batch[m] < g) lo = m + 1; else hi = m; }
    int start = lo;
    hi = N_NODES;
    while (lo < hi) { int m = (lo + hi) >> 1; if (batch[m] < g + 1) lo = m + 1; else hi = m; }
    float c = (float)(lo - start);
    out[g * D + lane] /= fmaxf(c, 1.0f);
}

// ---------------- launch ----------------
extern "C" void kernel_launch(void* const* d_in, const int* in_sizes, int n_in,
                              void* d_out, int out_size, void* d_ws, size_t ws_size,
                              hipStream_t stream) {
    const float* x     = (const float*)d_in[0];
    const int*   ei    = (const int*)d_in[1];
    const int*   src   = ei;
    const int*   dst   = ei + N_EDGES;
    const int*   batch = (const int*)d_in[2];
    const float* ew    = (const float*)d_in[3];
    const float* W1    = (const float*)d_in[4];
    const float* b1    = (const float*)d_in[5];
    const float* W2    = (const float*)d_in[6];
    const float* b2    = (const float*)d_in[7];
    float* out = (float*)d_out;

    char* ws = (char*)d_ws;
    float*  bufA   = (float*)(ws);                    // 25.6 MB  h1
    float2* csr    = (float2*)(ws + 25600000);        // 12.8 MB  (src, norm)
    float*  deg    = (float*)(ws + 38400000);         // 400 KB   deg -> dinv
    int*    cnt    = (int*)(ws + 38800000);           // 400 KB
    int*    rowptr = (int*)(ws + 39200000);           // 400 KB
    int*    cursor = (int*)(ws + 39600000);           // 400 KB
    int*    bsums  = (int*)(ws + 40000000);           // 2 KB

    // normalization + CSR build
    k_init<<<NBLK, 256, 0, stream>>>(deg, cnt, out);
    k_count_deg<<<(N_EDGES + 255) / 256, 256, 0, stream>>>(dst, ew, deg, cnt);
    k_dinv<<<NBLK, 256, 0, stream>>>(deg);
    k_scan1<<<NBLK, 256, 0, stream>>>(cnt, rowptr, bsums);
    k_scan2<<<1, 512, 0, stream>>>(bsums);
    k_scan3<<<NBLK, 256, 0, stream>>>(rowptr, cnt, bsums, rowptr, cursor);
    k_scatter<<<(N_EDGES + 255) / 256, 256, 0, stream>>>(src, dst, ew, deg, cursor, csr);

    // layer 1: bufA = relu((A x) W1 + b1)
    k_layer<1><<<2048, 256, 0, stream>>>(x, W1, b1, deg, rowptr, cnt, csr, batch, bufA);
    // layer 2 + pool-sum: out[g] += relu((A bufA) W2 + b2)
    k_layer<2><<<2048, 256, 0, stream>>>(bufA, W2, b2, deg, rowptr, cnt, csr, batch, out);
    // mean
    k_finalize<<<N_GRAPHS, D, 0, stream>>>(out, batch);
}

// Round 7
// 519.898 us; speedup vs baseline: 3.0056x; 1.0059x over previous
//
#include <hip/hip_runtime.h>

#define N_NODES 100000
#define N_EDGES 1600000
#define D 64
#define N_GRAPHS 64
#define NBLK ((N_NODES + 255) / 256)   // 391 scan blocks
#define WTS 68                         // WT row stride (floats): conflict-free

// ---------------- init: deg=1 (self loop), cnt=0, out=0 ----------------
__global__ void k_init(float* __restrict__ deg, int* __restrict__ cnt,
                       float* __restrict__ out) {
    int i = blockIdx.x * blockDim.x + threadIdx.x;
    if (i < N_NODES) { deg[i] = 1.0f; cnt[i] = 0; }
    if (i < N_GRAPHS * D) out[i] = 0.0f;
}

// ---------------- degree + in-edge count ----------------
__global__ void k_count_deg(const int* __restrict__ dst, const float* __restrict__ ew,
                            float* __restrict__ deg, int* __restrict__ cnt) {
    int e = blockIdx.x * blockDim.x + threadIdx.x;
    if (e < N_EDGES) {
        int d = dst[e];
        atomicAdd(&deg[d], ew[e]);
        atomicAdd(&cnt[d], 1);
    }
}

__global__ void k_dinv(float* __restrict__ deg) {
    int i = blockIdx.x * blockDim.x + threadIdx.x;
    if (i < N_NODES) {
        float d = deg[i];
        deg[i] = d > 0.f ? rsqrtf(d) : 0.f;
    }
}

// ---------------- exclusive scan of cnt -> rowptr ----------------
__global__ void k_scan1(const int* __restrict__ cnt, int* __restrict__ partial,
                        int* __restrict__ bsums) {
    int t = threadIdx.x, b = blockIdx.x, i = b * 256 + t;
    int v = (i < N_NODES) ? cnt[i] : 0;
    int incl = v;
    int lane = t & 63;
#pragma unroll
    for (int off = 1; off < 64; off <<= 1) {
        int u = __shfl_up(incl, off);
        if (lane >= off) incl += u;
    }
    __shared__ int wsum[4];
    int w = t >> 6;
    if (lane == 63) wsum[w] = incl;
    __syncthreads();
    int add = 0;
    for (int k = 0; k < w; ++k) add += wsum[k];
    incl += add;
    if (i < N_NODES) partial[i] = incl;
    if (t == 255) bsums[b] = incl;
}

__global__ void k_scan2(int* __restrict__ bsums) {
    __shared__ int s[512];
    int t = threadIdx.x;
    s[t] = (t < NBLK) ? bsums[t] : 0;
    __syncthreads();
    for (int off = 1; off < 512; off <<= 1) {
        int u = (t >= off) ? s[t - off] : 0;
        __syncthreads();
        s[t] += u;
        __syncthreads();
    }
    if (t < NBLK) bsums[t] = (t == 0) ? 0 : s[t - 1];  // exclusive
}

__global__ void k_scan3(const int* __restrict__ partial, const int* __restrict__ cnt,
                        const int* __restrict__ bsums, int* __restrict__ rowptr,
                        int* __restrict__ cursor) {
    int i = blockIdx.x * 256 + threadIdx.x;
    if (i < N_NODES) {
        int excl = partial[i] - cnt[i] + bsums[blockIdx.x];
        rowptr[i] = excl;
        cursor[i] = excl;
    }
}

// ---------------- scatter edges into CSR (src, norm) grouped by dst ----------
__global__ void k_scatter(const int* __restrict__ src, const int* __restrict__ dst,
                          const float* __restrict__ ew, const float* __restrict__ dinv,
                          int* __restrict__ cursor, float2* __restrict__ csr) {
    int e = blockIdx.x * blockDim.x + threadIdx.x;
    if (e < N_EDGES) {
        int s = src[e];
        int d = dst[e];
        float nrm = dinv[s] * ew[e] * dinv[d];
        int pos = atomicAdd(&cursor[d], 1);
        csr[pos] = make_float2(__int_as_float(s), nrm);
    }
}

// ---------------- fused layer ----------------
// One row per wave-iteration. 1024-thread blocks: 16 waves share one LDS copy
// (~21.8 KB) so 2 blocks = 32 waves fit per CU. Gather runs fully-predicated
// unroll-8 passes (clamped index, zeroed weight) — no serial scalar tail.
// GEMM: lane's W-column from transposed-W LDS (stride 68, conflict-free),
// acc broadcast via 1 ds_write + same-address float4 reads.
// LAYER==1: write relu(.)  LAYER==2: pool-atomicAdd relu(.) into out[batch].

#define EPASS(U)                                                              \
    {                                                                         \
        int  jj = j + (U);                                                    \
        int  ii = st + (jj < dgm1 ? jj : dgm1);                               \
        float2 e = csr[ii];                                                   \
        float  w = (jj < dg) ? e.y : 0.0f;                                    \
        int    s = __builtin_amdgcn_readfirstlane(__float_as_int(e.x));       \
        float  v = in[s * D + lane];                                          \
        acc = fmaf(v, w, acc);                                                \
    }

template <int LAYER>
__global__ __launch_bounds__(1024) void k_layer(
        const float* __restrict__ in, const float* __restrict__ W,
        const float* __restrict__ bias, const float* __restrict__ dinv,
        const int* __restrict__ rowptr, const int* __restrict__ cnt,
        const float2* __restrict__ csr, const int* __restrict__ batch,
        float* __restrict__ outp) {
    __shared__ float WTs[D * WTS];       // 17408 B transposed W
    __shared__ float aw[16][D];          // 4 KB per-wave row staging
    __shared__ float bs[D];

    {   // stage W transposed: WTs[c*WTS + k] = W[k*D + c]
        int t = threadIdx.x;
#pragma unroll
        for (int i = 0; i < 4; ++i) {
            int idx = t + i * 1024;
            int k = idx >> 6, c = idx & 63;
            WTs[c * WTS + k] = W[idx];
        }
        if (t < D) bs[t] = bias[t];
    }
    __syncthreads();

    const int lane = threadIdx.x & 63;
    const int wid  = threadIdx.x >> 6;
    float* awm = aw[wid];
    const float bl = bs[lane];

    int gw = (blockIdx.x * blockDim.x + threadIdx.x) >> 6;
    const int tw = (gridDim.x * blockDim.x) >> 6;

    for (int row = gw; row < N_NODES; row += tw) {
        const int st = __builtin_amdgcn_readfirstlane(rowptr[row]);
        const int dg = __builtin_amdgcn_readfirstlane(cnt[row]);
        const int dgm1 = dg - 1;
        float di = dinv[row];
        float acc = in[row * D + lane] * (di * di);   // self-loop

        const int passes = (dg + 7) >> 3;
        for (int p = 0; p < passes; ++p) {
            const int j = p * 8;
            // 8 independent predicated edges: all loads issue before the fmas
            int  jj0 = j + 0, jj1 = j + 1, jj2 = j + 2, jj3 = j + 3;
            int  jj4 = j + 4, jj5 = j + 5, jj6 = j + 6, jj7 = j + 7;
            float2 e0 = csr[st + (jj0 < dgm1 ? jj0 : dgm1)];
            float2 e1 = csr[st + (jj1 < dgm1 ? jj1 : dgm1)];
            float2 e2 = csr[st + (jj2 < dgm1 ? jj2 : dgm1)];
            float2 e3 = csr[st + (jj3 < dgm1 ? jj3 : dgm1)];
            float2 e4 = csr[st + (jj4 < dgm1 ? jj4 : dgm1)];
            float2 e5 = csr[st + (jj5 < dgm1 ? jj5 : dgm1)];
            float2 e6 = csr[st + (jj6 < dgm1 ? jj6 : dgm1)];
            float2 e7 = csr[st + (jj7 < dgm1 ? jj7 : dgm1)];
            float w0 = (jj0 < dg) ? e0.y : 0.f;
            float w1 = (jj1 < dg) ? e1.y : 0.f;
            float w2 = (jj2 < dg) ? e2.y : 0.f;
            float w3 = (jj3 < dg) ? e3.y : 0.f;
            float w4 = (jj4 < dg) ? e4.y : 0.f;
            float w5 = (jj5 < dg) ? e5.y : 0.f;
            float w6 = (jj6 < dg) ? e6.y : 0.f;
            float w7 = (jj7 < dg) ? e7.y : 0.f;
            int s0 = __builtin_amdgcn_readfirstlane(__float_as_int(e0.x));
            int s1 = __builtin_amdgcn_readfirstlane(__float_as_int(e1.x));
            int s2 = __builtin_amdgcn_readfirstlane(__float_as_int(e2.x));
            int s3 = __builtin_amdgcn_readfirstlane(__float_as_int(e3.x));
            int s4 = __builtin_amdgcn_readfirstlane(__float_as_int(e4.x));
            int s5 = __builtin_amdgcn_readfirstlane(__float_as_int(e5.x));
            int s6 = __builtin_amdgcn_readfirstlane(__float_as_int(e6.x));
            int s7 = __builtin_amdgcn_readfirstlane(__float_as_int(e7.x));
            float v0 = in[s0 * D + lane];
            float v1 = in[s1 * D + lane];
            float v2 = in[s2 * D + lane];
            float v3 = in[s3 * D + lane];
            float v4 = in[s4 * D + lane];
            float v5 = in[s5 * D + lane];
            float v6 = in[s6 * D + lane];
            float v7 = in[s7 * D + lane];
            acc = fmaf(v0, w0, acc);
            acc = fmaf(v1, w1, acc);
            acc = fmaf(v2, w2, acc);
            acc = fmaf(v3, w3, acc);
            acc = fmaf(v4, w4, acc);
            acc = fmaf(v5, w5, acc);
            acc = fmaf(v6, w6, acc);
            acc = fmaf(v7, w7, acc);
        }

        // ---- GEMM: r[lane] = sum_k acc[k] * W[k][lane] ----
        awm[lane] = acc;   // same-wave LDS RAW; compiler inserts lgkmcnt wait
        float r0 = 0.f, r1 = 0.f, r2 = 0.f, r3 = 0.f;
#pragma unroll
        for (int t = 0; t < 16; ++t) {
            float4 a = *(const float4*)&awm[t * 4];                // broadcast
            float4 w = *(const float4*)&WTs[lane * WTS + t * 4];   // conflict-free
            r0 = fmaf(a.x, w.x, r0);
            r1 = fmaf(a.y, w.y, r1);
            r2 = fmaf(a.z, w.z, r2);
            r3 = fmaf(a.w, w.w, r3);
        }
        float r = fmaxf((r0 + r1) + (r2 + r3) + bl, 0.f);

        if (LAYER == 1) {
            outp[row * D + lane] = r;
        } else {
            atomicAdd(&outp[batch[row] * D + lane], r);
        }
    }
}

// ---------------- finalize pool: divide by per-graph node count ----------------
__global__ void k_finalize(float* __restrict__ out, const int* __restrict__ batch) {
    int g = blockIdx.x;
    int lane = threadIdx.x;
    int lo = 0, hi = N_NODES;
    while (lo < hi) { int m = (lo + hi) >> 1; if (batch[m] < g) lo = m + 1; else hi = m; }
    int start = lo;
    hi = N_NODES;
    while (lo < hi) { int m = (lo + hi) >> 1; if (batch[m] < g + 1) lo = m + 1; else hi = m; }
    float c = (float)(lo - start);
    out[g * D + lane] /= fmaxf(c, 1.0f);
}

// ---------------- launch ----------------
extern "C" void kernel_launch(void* const* d_in, const int* in_sizes, int n_in,
                              void* d_out, int out_size, void* d_ws, size_t ws_size,
                              hipStream_t stream) {
    const float* x     = (const float*)d_in[0];
    const int*   ei    = (const int*)d_in[1];
    const int*   src   = ei;
    const int*   dst   = ei + N_EDGES;
    const int*   batch = (const int*)d_in[2];
    const float* ew    = (const float*)d_in[3];
    const float* W1    = (const float*)d_in[4];
    const float* b1    = (const float*)d_in[5];
    const float* W2    = (const float*)d_in[6];
    const float* b2    = (const float*)d_in[7];
    float* out = (float*)d_out;

    char* ws = (char*)d_ws;
    float*  bufA   = (float*)(ws);                    // 25.6 MB  h1
    float2* csr    = (float2*)(ws + 25600000);        // 12.8 MB  (src, norm)
    float*  deg    = (float*)(ws + 38400000);         // 400 KB   deg -> dinv
    int*    cnt    = (int*)(ws + 38800000);           // 400 KB
    int*    rowptr = (int*)(ws + 39200000);           // 400 KB
    int*    cursor = (int*)(ws + 39600000);           // 400 KB
    int*    bsums  = (int*)(ws + 40000000);           // 2 KB

    // normalization + CSR build
    k_init<<<NBLK, 256, 0, stream>>>(deg, cnt, out);
    k_count_deg<<<(N_EDGES + 255) / 256, 256, 0, stream>>>(dst, ew, deg, cnt);
    k_dinv<<<NBLK, 256, 0, stream>>>(deg);
    k_scan1<<<NBLK, 256, 0, stream>>>(cnt, rowptr, bsums);
    k_scan2<<<1, 512, 0, stream>>>(bsums);
    k_scan3<<<NBLK, 256, 0, stream>>>(rowptr, cnt, bsums, rowptr, cursor);
    k_scatter<<<(N_EDGES + 255) / 256, 256, 0, stream>>>(src, dst, ew, deg, cursor, csr);

    // layer 1: bufA = relu((A x) W1 + b1)
    k_layer<1><<<512, 1024, 0, stream>>>(x, W1, b1, deg, rowptr, cnt, csr, batch, bufA);
    // layer 2 + pool-sum: out[g] += relu((A bufA) W2 + b2)
    k_layer<2><<<512, 1024, 0, stream>>>(bufA, W2, b2, deg, rowptr, cnt, csr, batch, out);
    // mean
    k_finalize<<<N_GRAPHS, D, 0, stream>>>(out, batch);
}

// Round 8
// 473.429 us; speedup vs baseline: 3.3006x; 1.0982x over previous
//
#include <hip/hip_runtime.h>

#define N_NODES 100000
#define N_EDGES 1600000
#define D 64
#define N_GRAPHS 64
#define NBLK ((N_NODES + 255) / 256)   // 391 scan blocks
#define WTS 68                         // WT row stride (floats): conflict-free

// ---------------- init: deg=1 (self loop), cnt=0, out=0 ----------------
__global__ void k_init(float* __restrict__ deg, int* __restrict__ cnt,
                       float* __restrict__ out) {
    int i = blockIdx.x * blockDim.x + threadIdx.x;
    if (i < N_NODES) { deg[i] = 1.0f; cnt[i] = 0; }
    if (i < N_GRAPHS * D) out[i] = 0.0f;
}

// ---------------- degree + in-edge count ----------------
__global__ void k_count_deg(const int* __restrict__ dst, const float* __restrict__ ew,
                            float* __restrict__ deg, int* __restrict__ cnt) {
    int e = blockIdx.x * blockDim.x + threadIdx.x;
    if (e < N_EDGES) {
        int d = dst[e];
        atomicAdd(&deg[d], ew[e]);
        atomicAdd(&cnt[d], 1);
    }
}

__global__ void k_dinv(float* __restrict__ deg) {
    int i = blockIdx.x * blockDim.x + threadIdx.x;
    if (i < N_NODES) {
        float d = deg[i];
        deg[i] = d > 0.f ? rsqrtf(d) : 0.f;
    }
}

// ---------------- exclusive scan of cnt -> rowptr ----------------
__global__ void k_scan1(const int* __restrict__ cnt, int* __restrict__ partial,
                        int* __restrict__ bsums) {
    int t = threadIdx.x, b = blockIdx.x, i = b * 256 + t;
    int v = (i < N_NODES) ? cnt[i] : 0;
    int incl = v;
    int lane = t & 63;
#pragma unroll
    for (int off = 1; off < 64; off <<= 1) {
        int u = __shfl_up(incl, off);
        if (lane >= off) incl += u;
    }
    __shared__ int wsum[4];
    int w = t >> 6;
    if (lane == 63) wsum[w] = incl;
    __syncthreads();
    int add = 0;
    for (int k = 0; k < w; ++k) add += wsum[k];
    incl += add;
    if (i < N_NODES) partial[i] = incl;
    if (t == 255) bsums[b] = incl;
}

__global__ void k_scan2(int* __restrict__ bsums) {
    __shared__ int s[512];
    int t = threadIdx.x;
    s[t] = (t < NBLK) ? bsums[t] : 0;
    __syncthreads();
    for (int off = 1; off < 512; off <<= 1) {
        int u = (t >= off) ? s[t - off] : 0;
        __syncthreads();
        s[t] += u;
        __syncthreads();
    }
    if (t < NBLK) bsums[t] = (t == 0) ? 0 : s[t - 1];  // exclusive
}

__global__ void k_scan3(const int* __restrict__ partial, const int* __restrict__ cnt,
                        const int* __restrict__ bsums, int* __restrict__ rowptr,
                        int* __restrict__ cursor) {
    int i = blockIdx.x * 256 + threadIdx.x;
    if (i < N_NODES) {
        int excl = partial[i] - cnt[i] + bsums[blockIdx.x];
        rowptr[i] = excl;
        cursor[i] = excl;
    }
}

// ---------------- scatter edges into CSR (src, norm) grouped by dst ----------
__global__ void k_scatter(const int* __restrict__ src, const int* __restrict__ dst,
                          const float* __restrict__ ew, const float* __restrict__ dinv,
                          int* __restrict__ cursor, float2* __restrict__ csr) {
    int e = blockIdx.x * blockDim.x + threadIdx.x;
    if (e < N_EDGES) {
        int s = src[e];
        int d = dst[e];
        float nrm = dinv[s] * ew[e] * dinv[d];
        int pos = atomicAdd(&cursor[d], 1);
        csr[pos] = make_float2(__int_as_float(s), nrm);
    }
}

// ---------------- fused layer ----------------
// One row per wave-iteration. CSR entries for pass p+1 are register-
// double-buffered (prefetched during pass p) so gathers never wait on the
// csr load. Fully-predicated unroll-8 passes (clamped index, zeroed weight).
// GEMM: lane's W-column from transposed-W LDS (stride 68, conflict-free),
// acc broadcast via 1 ds_write + same-address float4 reads.
// LAYER==1: write relu(.)  LAYER==2: pool-atomicAdd relu(.) into out[batch].

// clamped csr index for edge slot jj of a row: safe for any dg>=0
#define CIDX(jj) (st + ((jj) < dgm1 ? ((jj) > 0 ? (jj) : 0) : (dgm1 > 0 ? dgm1 : 0)))

template <int LAYER>
__global__ __launch_bounds__(1024) void k_layer(
        const float* __restrict__ in, const float* __restrict__ W,
        const float* __restrict__ bias, const float* __restrict__ dinv,
        const int* __restrict__ rowptr, const int* __restrict__ cnt,
        const float2* __restrict__ csr, const int* __restrict__ batch,
        float* __restrict__ outp) {
    __shared__ float WTs[D * WTS];       // 17408 B transposed W
    __shared__ float aw[16][D];          // 4 KB per-wave row staging
    __shared__ float bs[D];

    {   // stage W transposed: WTs[c*WTS + k] = W[k*D + c]
        int t = threadIdx.x;
#pragma unroll
        for (int i = 0; i < 4; ++i) {
            int idx = t + i * 1024;
            int k = idx >> 6, c = idx & 63;
            WTs[c * WTS + k] = W[idx];
        }
        if (t < D) bs[t] = bias[t];
    }
    __syncthreads();

    const int lane = threadIdx.x & 63;
    const int wid  = threadIdx.x >> 6;
    float* awm = aw[wid];
    const float bl = bs[lane];

    int gw = (blockIdx.x * blockDim.x + threadIdx.x) >> 6;
    const int tw = (gridDim.x * blockDim.x) >> 6;

    for (int row = gw; row < N_NODES; row += tw) {
        const int st = __builtin_amdgcn_readfirstlane(rowptr[row]);
        const int dg = __builtin_amdgcn_readfirstlane(cnt[row]);
        const int dgm1 = dg - 1;
        float di = dinv[row];
        float acc = in[row * D + lane] * (di * di);   // self-loop

        const int passes = (dg + 7) >> 3;

        // prime pass-0 csr entries
        float2 e0 = csr[CIDX(0)];
        float2 e1 = csr[CIDX(1)];
        float2 e2 = csr[CIDX(2)];
        float2 e3 = csr[CIDX(3)];
        float2 e4 = csr[CIDX(4)];
        float2 e5 = csr[CIDX(5)];
        float2 e6 = csr[CIDX(6)];
        float2 e7 = csr[CIDX(7)];

        for (int p = 0; p < passes; ++p) {
            const int j = p * 8;
            const int jn = j + 8;
            // prefetch pass p+1 csr entries (clamped; harmless on last pass)
            float2 f0 = csr[CIDX(jn + 0)];
            float2 f1 = csr[CIDX(jn + 1)];
            float2 f2 = csr[CIDX(jn + 2)];
            float2 f3 = csr[CIDX(jn + 3)];
            float2 f4 = csr[CIDX(jn + 4)];
            float2 f5 = csr[CIDX(jn + 5)];
            float2 f6 = csr[CIDX(jn + 6)];
            float2 f7 = csr[CIDX(jn + 7)];

            // gathers from already-resident e[]: no csr wait on critical path
            float w0 = (j + 0 < dg) ? e0.y : 0.f;
            float w1 = (j + 1 < dg) ? e1.y : 0.f;
            float w2 = (j + 2 < dg) ? e2.y : 0.f;
            float w3 = (j + 3 < dg) ? e3.y : 0.f;
            float w4 = (j + 4 < dg) ? e4.y : 0.f;
            float w5 = (j + 5 < dg) ? e5.y : 0.f;
            float w6 = (j + 6 < dg) ? e6.y : 0.f;
            float w7 = (j + 7 < dg) ? e7.y : 0.f;
            int s0 = __builtin_amdgcn_readfirstlane(__float_as_int(e0.x));
            int s1 = __builtin_amdgcn_readfirstlane(__float_as_int(e1.x));
            int s2 = __builtin_amdgcn_readfirstlane(__float_as_int(e2.x));
            int s3 = __builtin_amdgcn_readfirstlane(__float_as_int(e3.x));
            int s4 = __builtin_amdgcn_readfirstlane(__float_as_int(e4.x));
            int s5 = __builtin_amdgcn_readfirstlane(__float_as_int(e5.x));
            int s6 = __builtin_amdgcn_readfirstlane(__float_as_int(e6.x));
            int s7 = __builtin_amdgcn_readfirstlane(__float_as_int(e7.x));
            float v0 = in[s0 * D + lane];
            float v1 = in[s1 * D + lane];
            float v2 = in[s2 * D + lane];
            float v3 = in[s3 * D + lane];
            float v4 = in[s4 * D + lane];
            float v5 = in[s5 * D + lane];
            float v6 = in[s6 * D + lane];
            float v7 = in[s7 * D + lane];
            acc = fmaf(v0, w0, acc);
            acc = fmaf(v1, w1, acc);
            acc = fmaf(v2, w2, acc);
            acc = fmaf(v3, w3, acc);
            acc = fmaf(v4, w4, acc);
            acc = fmaf(v5, w5, acc);
            acc = fmaf(v6, w6, acc);
            acc = fmaf(v7, w7, acc);

            e0 = f0; e1 = f1; e2 = f2; e3 = f3;
            e4 = f4; e5 = f5; e6 = f6; e7 = f7;
        }

        // ---- GEMM: r[lane] = sum_k acc[k] * W[k][lane] ----
        awm[lane] = acc;   // same-wave LDS RAW; compiler inserts lgkmcnt wait
        float r0 = 0.f, r1 = 0.f, r2 = 0.f, r3 = 0.f;
#pragma unroll
        for (int t = 0; t < 16; ++t) {
            float4 a = *(const float4*)&awm[t * 4];                // broadcast
            float4 w = *(const float4*)&WTs[lane * WTS + t * 4];   // conflict-free
            r0 = fmaf(a.x, w.x, r0);
            r1 = fmaf(a.y, w.y, r1);
            r2 = fmaf(a.z, w.z, r2);
            r3 = fmaf(a.w, w.w, r3);
        }
        float r = fmaxf((r0 + r1) + (r2 + r3) + bl, 0.f);

        if (LAYER == 1) {
            outp[row * D + lane] = r;
        } else {
            atomicAdd(&outp[batch[row] * D + lane], r);
        }
    }
}

// ---------------- finalize pool: divide by per-graph node count ----------------
__global__ void k_finalize(float* __restrict__ out, const int* __restrict__ batch) {
    int g = blockIdx.x;
    int lane = threadIdx.x;
    int lo = 0, hi = N_NODES;
    while (lo < hi) { int m = (lo + hi) >> 1; if (batch[m] < g) lo = m + 1; else hi = m; }
    int start = lo;
    hi = N_NODES;
    while (lo < hi) { int m = (lo + hi) >> 1; if (batch[m] < g + 1) lo = m + 1; else hi = m; }
    float c = (float)(lo - start);
    out[g * D + lane] /= fmaxf(c, 1.0f);
}

// ---------------- launch ----------------
extern "C" void kernel_launch(void* const* d_in, const int* in_sizes, int n_in,
                              void* d_out, int out_size, void* d_ws, size_t ws_size,
                              hipStream_t stream) {
    const float* x     = (const float*)d_in[0];
    const int*   ei    = (const int*)d_in[1];
    const int*   src   = ei;
    const int*   dst   = ei + N_EDGES;
    const int*   batch = (const int*)d_in[2];
    const float* ew    = (const float*)d_in[3];
    const float* W1    = (const float*)d_in[4];
    const float* b1    = (const float*)d_in[5];
    const float* W2    = (const float*)d_in[6];
    const float* b2    = (const float*)d_in[7];
    float* out = (float*)d_out;

    char* ws = (char*)d_ws;
    float*  bufA   = (float*)(ws);                    // 25.6 MB  h1
    float2* csr    = (float2*)(ws + 25600000);        // 12.8 MB  (src, norm)
    float*  deg    = (float*)(ws + 38400000);         // 400 KB   deg -> dinv
    int*    cnt    = (int*)(ws + 38800000);           // 400 KB
    int*    rowptr = (int*)(ws + 39200000);           // 400 KB
    int*    cursor = (int*)(ws + 39600000);           // 400 KB
    int*    bsums  = (int*)(ws + 40000000);           // 2 KB

    // normalization + CSR build
    k_init<<<NBLK, 256, 0, stream>>>(deg, cnt, out);
    k_count_deg<<<(N_EDGES + 255) / 256, 256, 0, stream>>>(dst, ew, deg, cnt);
    k_dinv<<<NBLK, 256, 0, stream>>>(deg);
    k_scan1<<<NBLK, 256, 0, stream>>>(cnt, rowptr, bsums);
    k_scan2<<<1, 512, 0, stream>>>(bsums);
    k_scan3<<<NBLK, 256, 0, stream>>>(rowptr, cnt, bsums, rowptr, cursor);
    k_scatter<<<(N_EDGES + 255) / 256, 256, 0, stream>>>(src, dst, ew, deg, cursor, csr);

    // layer 1: bufA = relu((A x) W1 + b1)
    k_layer<1><<<512, 1024, 0, stream>>>(x, W1, b1, deg, rowptr, cnt, csr, batch, bufA);
    // layer 2 + pool-sum: out[g] += relu((A bufA) W2 + b2)
    k_layer<2><<<512, 1024, 0, stream>>>(bufA, W2, b2, deg, rowptr, cnt, csr, batch, out);
    // mean
    k_finalize<<<N_GRAPHS, D, 0, stream>>>(out, batch);
}